// Round 8
// baseline (1640.755 us; speedup 1.0000x reference)
//
#include <hip/hip_runtime.h>

#define B_ 16
#define N_ 1024
#define M_ 4096
#define D_ 64
#define SROWS_ (N_ + 63)        // 1087 valid skewed steps per tile
#define SROWSP_ (SROWS_ + 17)   // padded stride (16-deep refill overrun)
#define SPAIR_ 544              // step-pairs per tile
#define TSB_ ((size_t)SPAIR_ * 128)  // dec bytes per tile (69632)
#define BTQ_ 96                 // backtrack window quads (384 cells)

__device__ __forceinline__ float finf() { return __builtin_inff(); }

__device__ __forceinline__ float wave_shr1(float x) {
  return __int_as_float(__builtin_amdgcn_update_dpp(
      0, __float_as_int(x), 0x138, 0xF, 0xF, false));
}
__device__ __forceinline__ float rdlane(float v, int l) {
  return __int_as_float(__builtin_amdgcn_readlane(__float_as_int(v), l));
}

// ---------------------------------------------------------------------------
__global__ void prep_kernel(const float* __restrict__ x,
                            const float* __restrict__ x_t,
                            float* __restrict__ x2,
                            float* __restrict__ w_ts_out) {
  int id = blockIdx.x * blockDim.x + threadIdx.x;
  const float4* xr = (const float4*)(x + (size_t)id * D_);
  float s = 0.f;
#pragma unroll
  for (int e = 0; e < D_ / 4; ++e) {
    float4 v = xr[e];
    s += v.x * v.x + v.y * v.y + v.z * v.z + v.w * v.w;
  }
  x2[id] = s;
  w_ts_out[id] = x_t[id];
}

// ---------------------------------------------------------------------------
// GEMM writing C pre-skewed per 256-col tile: Cs[tile][(i+l)*256 + ct], l=ct>>2.
// ---------------------------------------------------------------------------
__global__ __launch_bounds__(256) void gemm_kernel(
    const float* __restrict__ x, const float* __restrict__ y,
    const float* __restrict__ x2, float* __restrict__ Cs, int chunkBase) {
  const int b = blockIdx.z;
  const int tile = blockIdx.x;
  const int lane = threadIdx.x & 63;
  const int wid = threadIdx.x >> 6;
  const int ct = wid * 64 + lane;
  const int j = chunkBase + tile * 256 + ct;
  const int l = ct >> 2;
  float* CsT = Cs + (size_t)(b * 4 + tile) * SROWSP_ * 256;

  const float4* yrow = (const float4*)(y + ((size_t)b * M_ + j) * D_);
  float4 yr[D_ / 4];
#pragma unroll
  for (int e = 0; e < D_ / 4; ++e) yr[e] = yrow[e];
  float y2 = 0.f;
#pragma unroll
  for (int e = 0; e < D_ / 4; ++e)
    y2 += yr[e].x * yr[e].x + yr[e].y * yr[e].y + yr[e].z * yr[e].z + yr[e].w * yr[e].w;

  const int ibeg = blockIdx.y * 128;
  for (int i = ibeg; i < ibeg + 128; ++i) {
    const float4* xr = (const float4*)(x + ((size_t)b * N_ + i) * D_);
    float acc = 0.f;
#pragma unroll
    for (int e = 0; e < D_ / 4; ++e) {
      float4 xv = xr[e];
      acc += xv.x * yr[e].x + xv.y * yr[e].y + xv.z * yr[e].z + xv.w * yr[e].w;
    }
    CsT[(size_t)(i + l) * 256 + ct] = x2[b * N_ + i] + y2 - 2.f * acc;
  }
}

// ---------------------------------------------------------------------------
// Systolic DP: 2 INDEPENDENT batches per 512-thread WG (2 waves/SIMD from
// different pipelines -> latency overlap without R6's coupling). Wave W of
// group g owns a 256-col tile of batch b=blockIdx.x*2+g; lane l owns 4 cols;
// step s => row i = s - lane. Full-column LDS edge buffer, publishes batched
// per 8 rows, poll once/block (+24-row startup slack). 16-row-deep named-reg
// C prefetch (two 8-reg banks). dec packed ushort (2 steps/store).
// ---------------------------------------------------------------------------
__global__ __launch_bounds__(512) void dtw_dp(
    const float* __restrict__ Cs, unsigned char* __restrict__ dec,
    const float* __restrict__ carryIn, float* __restrict__ carryOut,
    float* __restrict__ partV, int* __restrict__ partJ,
    int chunk, int hasCarry) {
  const int t = threadIdx.x;
  const int g = t >> 8;
  const int tg = t & 255;
  const int lane = tg & 63;
  const int W = tg >> 6;
  const int b = blockIdx.x * 2 + g;

  __shared__ float ring[2][3][1024];
  __shared__ float cring[2][1024];
  __shared__ int prog[2][3];
  __shared__ float redV[2][4];
  __shared__ int redJ[2][4];
  volatile int* vProgG = prog[g];

  if (tg < 3) prog[g][tg] = -1;
  const float* cIn = carryIn + b * N_;
  if (hasCarry) ((float4*)cring[g])[tg] = ((const float4*)cIn)[tg];
  __syncthreads();

  const float INF = finf();
  const float* loadP = Cs + (size_t)(b * 4 + W) * SROWSP_ * 256;
  const int tileG = chunk * 4 + W;
  unsigned short* decP =
      (unsigned short*)(dec + (size_t)(b * 16 + tileG) * TSB_) + lane;
  float* carryB = carryOut + b * N_;
  const int jbase = tileG * 256 + lane * 4;
  const float* ringR = ring[g][W > 0 ? W - 1 : 0];
  volatile float* ringW = ring[g][W < 3 ? W : 0];
  const float* cringG = cring[g];

  float4 cc0 = ((const float4*)(loadP + 0 * 256))[lane];
  float4 cc1 = ((const float4*)(loadP + 1 * 256))[lane];
  float4 cc2 = ((const float4*)(loadP + 2 * 256))[lane];
  float4 cc3 = ((const float4*)(loadP + 3 * 256))[lane];
  float4 cc4 = ((const float4*)(loadP + 4 * 256))[lane];
  float4 cc5 = ((const float4*)(loadP + 5 * 256))[lane];
  float4 cc6 = ((const float4*)(loadP + 6 * 256))[lane];
  float4 cc7 = ((const float4*)(loadP + 7 * 256))[lane];
  float4 cc8 = ((const float4*)(loadP + 8 * 256))[lane];
  float4 cc9 = ((const float4*)(loadP + 9 * 256))[lane];
  float4 cc10 = ((const float4*)(loadP + 10 * 256))[lane];
  float4 cc11 = ((const float4*)(loadP + 11 * 256))[lane];
  float4 cc12 = ((const float4*)(loadP + 12 * 256))[lane];
  float4 cc13 = ((const float4*)(loadP + 13 * 256))[lane];
  float4 cc14 = ((const float4*)(loadP + 14 * 256))[lane];
  float4 cc15 = ((const float4*)(loadP + 15 * 256))[lane];
  loadP += 16 * 256;

  float edgeVec = INF, lvPrev = INF;
  float up0 = 0.f, up1 = 0.f, up2 = 0.f, up3 = 0.f;
  float dpp1 = INF, dpp2 = INF;
  float fin0 = INF, fin1 = INF, fin2 = INF, fin3 = INF;
  float ebuf[8];

#define BLOCKHEAD()                                                           \
  {                                                                           \
    if (W > 0) {                                                              \
      if (sb < N_) {                                                          \
        int tgt = sb + 7;                                                     \
        if (sb == 0) tgt = 31;                                                \
        while (vProgG[W - 1] < tgt) __builtin_amdgcn_s_sleep(1);              \
        asm volatile("" ::: "memory");                                        \
        lvPrev = rdlane(edgeVec, 7);                                          \
        edgeVec = ringR[(sb + lane) & 1023];                                  \
      }                                                                       \
    } else if (hasCarry) {                                                    \
      lvPrev = rdlane(edgeVec, 7);                                            \
      if (sb < N_) edgeVec = cringG[(sb + lane) & 1023];                      \
    }                                                                         \
  }

#define DPSTEP(KK, CCV, ROW0, FIN)                                           \
  {                                                                          \
    const float lv = rdlane(edgeVec, (KK));                                  \
    const float left = (lane == 0) ? lv : dpp1;                              \
    const float diag = (lane == 0) ? lvPrev : dpp2;                          \
    lvPrev = lv;                                                             \
    float m0 = fminf(up0, left);                                             \
    float bv0 = fminf(diag, m0);                                             \
    unsigned int pk = (diag <= m0) ? 0u : ((up0 <= left) ? 1u : 2u);         \
    if (ROW0) bv0 = (sb + (KK) == lane) ? 0.f : bv0;                         \
    const float D0 = CCV.x + bv0;                                            \
    float m1 = fminf(up1, D0);                                               \
    float bv1 = fminf(up0, m1);                                              \
    pk |= ((up0 <= m1) ? 0u : ((up1 <= D0) ? 1u : 2u)) << 2;                 \
    if (ROW0) bv1 = (sb + (KK) == lane) ? 0.f : bv1;                         \
    const float D1 = CCV.y + bv1;                                            \
    float m2 = fminf(up2, D1);                                               \
    float bv2 = fminf(up1, m2);                                              \
    pk |= ((up1 <= m2) ? 0u : ((up2 <= D1) ? 1u : 2u)) << 4;                 \
    if (ROW0) bv2 = (sb + (KK) == lane) ? 0.f : bv2;                         \
    const float D2 = CCV.z + bv2;                                            \
    float m3 = fminf(up3, D2);                                               \
    float bv3 = fminf(up2, m3);                                              \
    pk |= ((up2 <= m3) ? 0u : ((up3 <= D2) ? 1u : 2u)) << 6;                 \
    if (ROW0) bv3 = (sb + (KK) == lane) ? 0.f : bv3;                         \
    const float D3 = CCV.w + bv3;                                            \
    ebuf[(KK)] = D3;                                                         \
    if ((KK) & 1) {                                                          \
      pk16 |= pk << 8;                                                       \
      decP[((KK) >> 1) * 64] = (unsigned short)pk16;                         \
    } else {                                                                 \
      pk16 = pk;                                                             \
    }                                                                        \
    if (FIN) {                                                               \
      const bool lr = (sb + (KK) == 1023 + lane);                            \
      fin0 = lr ? D0 : fin0; fin1 = lr ? D1 : fin1;                          \
      fin2 = lr ? D2 : fin2; fin3 = lr ? D3 : fin3;                          \
    }                                                                        \
    const float sh = wave_shr1(D3);                                          \
    dpp2 = dpp1; dpp1 = sh;                                                  \
    up0 = D0; up1 = D1; up2 = D2; up3 = D3;                                  \
    CCV = ((const float4*)(loadP + (KK) * 256))[lane];                       \
  }

#define BLOCKEND()                                                           \
  {                                                                          \
    const int r0 = sb - 63;                                                  \
    if (W < 3) {                                                             \
      if (lane == 63 && r0 > -8 && r0 < N_) {                                \
        _Pragma("unroll") for (int k = 0; k < 8; ++k) {                      \
          const int r = r0 + k;                                              \
          if ((unsigned)r < (unsigned)N_) ringW[r] = ebuf[k];                \
        }                                                                    \
        __builtin_amdgcn_s_waitcnt(0xC07F);                                  \
        vProgG[W] = r0 + 7;                                                  \
      }                                                                      \
    } else if (chunk < 3) {                                                  \
      if (lane == 63 && r0 > -8 && r0 < N_) {                                \
        _Pragma("unroll") for (int k = 0; k < 8; ++k) {                      \
          const int r = r0 + k;                                              \
          if ((unsigned)r < (unsigned)N_) carryB[r] = ebuf[k];               \
        }                                                                    \
      }                                                                      \
    }                                                                        \
    loadP += 8 * 256;                                                        \
    decP += 256;                                                             \
  }

#define STEP8A(R0, FN)                                                       \
  DPSTEP(0, cc0, R0, FN) DPSTEP(1, cc1, R0, FN) DPSTEP(2, cc2, R0, FN)       \
  DPSTEP(3, cc3, R0, FN) DPSTEP(4, cc4, R0, FN) DPSTEP(5, cc5, R0, FN)       \
  DPSTEP(6, cc6, R0, FN) DPSTEP(7, cc7, R0, FN)
#define STEP8B(R0, FN)                                                       \
  DPSTEP(0, cc8, R0, FN) DPSTEP(1, cc9, R0, FN) DPSTEP(2, cc10, R0, FN)      \
  DPSTEP(3, cc11, R0, FN) DPSTEP(4, cc12, R0, FN) DPSTEP(5, cc13, R0, FN)    \
  DPSTEP(6, cc14, R0, FN) DPSTEP(7, cc15, R0, FN)

#define ITER16(R0a, FNa, R0b, FNb)                                           \
  {                                                                          \
    BLOCKHEAD();                                                             \
    { unsigned int pk16; STEP8A(R0a, FNa) }                                  \
    BLOCKEND();                                                              \
    sb += 8;                                                                 \
    BLOCKHEAD();                                                             \
    { unsigned int pk16; STEP8B(R0b, FNb) }                                  \
    BLOCKEND();                                                              \
    sb += 8;                                                                 \
  }

  int sb = 0;
  for (int it = 0; it < 4; ++it) ITER16(1, 0, 1, 0);    // sb 0..63 (row0)
  for (int it = 0; it < 59; ++it) ITER16(0, 0, 0, 0);   // sb 64..1007
  ITER16(0, 0, 0, 1);                                   // sb 1008..1023
  for (int it = 0; it < 4; ++it) ITER16(0, 1, 0, 1);    // sb 1024..1087 (fin)
#undef DPSTEP
#undef STEP8A
#undef STEP8B
#undef ITER16
#undef BLOCKHEAD
#undef BLOCKEND

  float mv = fin0; int mj = jbase;
  if (fin1 < mv) { mv = fin1; mj = jbase + 1; }
  if (fin2 < mv) { mv = fin2; mj = jbase + 2; }
  if (fin3 < mv) { mv = fin3; mj = jbase + 3; }
#pragma unroll
  for (int off = 32; off > 0; off >>= 1) {
    const float ov = __shfl_down(mv, off);
    const int oj = __shfl_down(mj, off);
    if (ov < mv || (ov == mv && oj < mj)) { mv = ov; mj = oj; }
  }
  if (lane == 0) { redV[g][W] = mv; redJ[g][W] = mj; }
  __syncthreads();
  if (tg == 0) {
    float bm = redV[g][0]; int bj = redJ[g][0];
#pragma unroll
    for (int w = 1; w < 4; ++w)
      if (redV[g][w] < bm) { bm = redV[g][w]; bj = redJ[g][w]; }
    partV[b * 4 + chunk] = bm;
    partJ[b * 4 + chunk] = bj;
  }
}

// ---------------------------------------------------------------------------
// Backtrack: 256 threads = 4 threads/row x 64 rows per super-step. Each
// thread loads 24 window bytes and builds its quarter of the run-exit table;
// a two-phase patch stitches runs across the 4 sub-blocks; lane-0 walk reads
// 1 LDS entry per row; parallel y_t gather.
// ---------------------------------------------------------------------------
__global__ __launch_bounds__(256) void backtrack_kernel(
    const unsigned char* __restrict__ dec, const float* __restrict__ partV,
    const int* __restrict__ partJ, const float* __restrict__ y_t,
    float* __restrict__ w_vs, float* __restrict__ cost_out) {
  const int b = blockIdx.x;
  const int t = threadIdx.x;
  const int rowIdx = t >> 2;
  const int sub = t & 3;
  __shared__ unsigned short tab[64][BTQ_ * 4 + 2];
  __shared__ unsigned short lastv[64][4];
  __shared__ int st_i, st_j;
  __shared__ int jrow[65];
  const unsigned char* db = dec + (size_t)b * 16 * TSB_;
  const float* yt = y_t + b * M_;
  float* wv = w_vs + b * N_;

  if (t == 0) {
    float bc = finf(); int bj = 0;
    for (int c = 0; c < 4; ++c) {  // chunks ascend in j: strict < keeps first
      const float v = partV[b * 4 + c];
      if (v < bc) { bc = v; bj = partJ[b * 4 + c]; }
    }
    cost_out[b] = bc;
    st_i = N_ - 1;
    st_j = bj;
    wv[N_ - 1] = yt[bj];
  }
  for (;;) {
    __syncthreads();
    const int i = st_i, j = st_j;
    if (i <= 0) break;
    int qlo = (j >> 2) - (BTQ_ - 1);
    if (qlo < 0) qlo = 0;
    const int r = i - rowIdx;
    const int cbase = sub * 96;  // 24 quads = 96 cells per sub-thread
    int patchEnd = 0;
    if (r >= 1) {
      unsigned char by[24];
      const int q0 = qlo + sub * 24;
#pragma unroll
      for (int k = 0; k < 24; ++k) {
        const int q = q0 + k;
        const int l = q & 63;
        const int s = r + l;
        by[k] = db[(size_t)(q >> 6) * TSB_ + (size_t)(s >> 1) * 128 + l * 2 + (s & 1)];
      }
      unsigned int run = 0xFFFF;
      int fs = -1;
#pragma unroll
      for (int k = 0; k < 24; ++k) {
        const unsigned int byte = by[k];
#pragma unroll
        for (int cs = 0; cs < 4; ++cs) {
          const unsigned int code = (byte >> (2 * cs)) & 3u;
          const int cloc = 4 * k + cs;
          if (code != 2u) {
            run = (unsigned int)(((cbase + cloc) << 2) | code);
            if (fs < 0) fs = cloc;
          }
          tab[rowIdx][cbase + cloc] = (unsigned short)run;
        }
      }
      lastv[rowIdx][sub] = (unsigned short)run;
      patchEnd = (fs < 0) ? 96 : fs;
    }
    __syncthreads();
    if (r >= 1 && sub > 0 && patchEnd > 0) {
      unsigned short inc = 0xFFFF;
      for (int s2 = 0; s2 < sub; ++s2) {
        const unsigned short lv = lastv[rowIdx][s2];
        if (lv != 0xFFFF) inc = lv;
      }
      if (inc != 0xFFFF) {
        for (int k = 0; k < patchEnd; ++k) tab[rowIdx][cbase + k] = inc;
      }
    }
    __syncthreads();
    if (t == 0) {
      const int base = qlo << 2;
      int rr = i, cj = j;
      while (rr >= 1 && (i - rr) < 64) {
        const int l = i - rr;
        const int c = cj - base;
        if (c < 0) break;  // window exhausted; restart
        const unsigned short v = tab[l][c];
        if (v == 0xFFFF) { cj = base - 1; break; }  // left-run exits window
        cj = base + (int)(v >> 2) - (((v & 3) == 0) ? 1 : 0);
        --rr;
        jrow[i - rr] = cj;
      }
      st_i = rr;
      st_j = cj;
    }
    __syncthreads();
    const int cnt = i - st_i;
    if (t < cnt) wv[i - 1 - t] = yt[jrow[t + 1]];
  }
}

// ---------------------------------------------------------------------------
extern "C" void kernel_launch(void* const* d_in, const int* in_sizes, int n_in,
                              void* d_out, int out_size, void* d_ws, size_t ws_size,
                              hipStream_t stream) {
  const float* x = (const float*)d_in[0];
  const float* y = (const float*)d_in[1];
  const float* x_t = (const float*)d_in[2];
  const float* y_t = (const float*)d_in[3];

  float* out_cost = (float*)d_out;      // [B_]
  float* out_wts = out_cost + B_;       // [B_][N_]
  float* out_wvs = out_wts + B_ * N_;   // [B_][N_]

  const size_t csBytes = (size_t)B_ * 4 * SROWSP_ * 256 * 4;  // ~72.4 MB
  const size_t decBytes = (size_t)B_ * 16 * TSB_;             // ~17.8 MB
  const size_t x2Bytes = (size_t)B_ * N_ * 4;

  char* ws = (char*)d_ws;
  float* Cs = (float*)ws;
  unsigned char* dec = (unsigned char*)(ws + csBytes);
  float* x2 = (float*)(ws + csBytes + decBytes);
  float* carryA = (float*)(ws + csBytes + decBytes + x2Bytes);
  float* carryB = carryA + B_ * N_;
  float* partV = carryB + B_ * N_;
  int* partJ = (int*)(partV + B_ * 4);

  prep_kernel<<<dim3((B_ * N_) / 256), 256, 0, stream>>>(x, x_t, x2, out_wts);

  float* cbuf[2] = {carryA, carryB};
  for (int c = 0; c < 4; ++c) {
    gemm_kernel<<<dim3(4, N_ / 128, B_), 256, 0, stream>>>(x, y, x2, Cs,
                                                           c * 1024);
    const float* cin = cbuf[(c + 1) & 1];
    float* cout = cbuf[c & 1];
    dtw_dp<<<dim3(B_ / 2), 512, 0, stream>>>(Cs, dec, cin, cout, partV, partJ,
                                             c, c > 0 ? 1 : 0);
  }

  backtrack_kernel<<<dim3(B_), 256, 0, stream>>>(dec, partV, partJ, y_t,
                                                 out_wvs, out_cost);
}